// Round 5
// baseline (46484.171 us; speedup 1.0000x reference)
//
#include <hip/hip_runtime.h>
#include <math.h>

#define N_NODES 10000
#define N_EDGES 100000
#define NB      64
#define EMB     100
#define H       2000
#define LAYERS  4

#define C1_OC 50
#define C1_L  666
#define C2_OC 100
#define C2_L  221
#define C3_OC 150
#define C3_L  73
#define LIN1_IN  10950
#define LIN1_OUT 500

// fp16 GEMM geometry
#define SEG  2016          // K = H padded to 32
#define MP   10112         // M = N_NODES padded to 128
#define NW   2048          // Wg output cols padded to 128 (and to 256-tile)
#define KK2  4032          // concat K for GRU ([Agg | Hc])
#define NPACK 8192         // 4 gates * 2048 h-cols, gate-interleaved per 16 (padded to 256)

using half8 = __attribute__((ext_vector_type(8))) _Float16;
using f32x4 = __attribute__((ext_vector_type(4))) float;

__device__ inline void gload16(const void* g, void* l) {
  __builtin_amdgcn_global_load_lds(
      (const __attribute__((address_space(1))) unsigned int*)g,
      (__attribute__((address_space(3))) unsigned int*)l, 16, 0, 0);
}

// ---------------- embedding -> fp16 h ----------------
__global__ void embed16_kernel(const int* __restrict__ tokens,
                               const float* __restrict__ table,
                               _Float16* __restrict__ h) {
  int n = blockIdx.x;
  int tok = tokens[n];
  for (int c = threadIdx.x; c < SEG; c += 256) {
    float v = (c < EMB) ? table[tok * EMB + c] : 0.f;
    h[(size_t)n * SEG + c] = (_Float16)v;
  }
}

// ---------------- CSR build ----------------
__global__ void hist_kernel(const int* __restrict__ dst, int* __restrict__ counts, int e) {
  int i = blockIdx.x * 256 + threadIdx.x;
  if (i < e) atomicAdd(&counts[dst[i]], 1);
}

__global__ void scan_kernel(const int* __restrict__ counts, int* __restrict__ row_off, int n) {
  __shared__ int sums[1024];
  int tid = threadIdx.x;
  const int CH = (n + 1023) / 1024;
  int start = tid * CH;
  int local = 0;
  for (int i = 0; i < CH; i++)
    if (start + i < n) local += counts[start + i];
  sums[tid] = local;
  __syncthreads();
  for (int off = 1; off < 1024; off <<= 1) {
    int v = (tid >= off) ? sums[tid - off] : 0;
    __syncthreads();
    sums[tid] += v;
    __syncthreads();
  }
  int run = (tid > 0) ? sums[tid - 1] : 0;
  for (int i = 0; i < CH; i++)
    if (start + i < n) { row_off[start + i] = run; run += counts[start + i]; }
  if (tid == 1023) row_off[n] = run;
}

__global__ void scatter_kernel(const int* __restrict__ src, const int* __restrict__ dst,
                               const int* __restrict__ row_off, int* __restrict__ cursor,
                               int* __restrict__ csr_src, int e) {
  int i = blockIdx.x * 256 + threadIdx.x;
  if (i < e) {
    int d = dst[i];
    int pos = atomicAdd(&cursor[d], 1);
    csr_src[row_off[d] + pos] = src[i];
  }
}

__global__ void starts_kernel(const int* __restrict__ batch, int* __restrict__ starts, int n) {
  int i = blockIdx.x * 256 + threadIdx.x;
  if (i >= n) return;
  int b = batch[i];
  int pb = (i == 0) ? -1 : batch[i - 1];
  if (b != pb)
    for (int x = pb + 1; x <= b; x++) starts[x] = i;
  if (i == n - 1)
    for (int x = b + 1; x <= NB; x++) starts[x] = n;
}

// ---------------- weight prep ----------------
// W_ggc[l] (H x H) -> transposed fp16 Bt: out[l][n][k] = W[k][n], n<NW, k<SEG
__global__ void prep_wg16_kernel(const float* __restrict__ Wg, _Float16* __restrict__ out) {
  __shared__ float t[32][33];
  int l = blockIdx.z;
  const float* W = Wg + (size_t)l * H * H;
  _Float16* o = out + (size_t)l * NW * SEG;
  int kt = blockIdx.x * 32, nt = blockIdx.y * 32;
  int tx = threadIdx.x & 31, ty = threadIdx.x >> 5;  // ty 0..7
#pragma unroll
  for (int i = 0; i < 4; i++) {
    int k = kt + ty + i * 8, n = nt + tx;
    t[tx][ty + i * 8] = (k < H && n < H) ? W[(size_t)k * H + n] : 0.f;
  }
  __syncthreads();
#pragma unroll
  for (int i = 0; i < 4; i++) {
    int nl = ty + i * 8, kl = tx;
    o[(size_t)(nt + nl) * SEG + (kt + kl)] = (_Float16)t[nl][kl];
  }
}

// Packed GRU weight matrix Wp: NPACK rows x KK2 cols.
// row n: gate=(n>>4)&3, hcol=(n>>6)*16+(n&15)
// gate0 (r): [Wih_r | Whh_r]; gate1 (z): [Wih_z | Whh_z]
// gate2 (inn): [Wih_n | 0];   gate3 (hn): [0 | Whh_n]
__global__ void prep_wpack_kernel(const float* __restrict__ Wih, const float* __restrict__ Whh,
                                  _Float16* __restrict__ out) {
  int n = blockIdx.y;
  int k = blockIdx.x * 256 + threadIdx.x;
  if (k >= KK2) return;
  int gate = (n >> 4) & 3;
  int hcol = ((n >> 6) << 4) + (n & 15);
  float v = 0.f;
  if (hcol < H) {
    if (gate < 2) {
      int row = gate * H + hcol;
      if (k < 2016) { if (k < H) v = Wih[(size_t)row * H + k]; }
      else { int k2 = k - 2016; if (k2 < H) v = Whh[(size_t)row * H + k2]; }
    } else if (gate == 2) {
      if (k < H) v = Wih[(size_t)(2 * H + hcol) * H + k];
    } else {
      int k2 = k - 2016;
      if (k2 >= 0 && k2 < H) v = Whh[(size_t)(2 * H + hcol) * H + k2];
    }
  }
  out[(size_t)n * KK2 + k] = (_Float16)v;
}

// ---------------- fp16 GEMM (panel-major LDS, 64x128/wave): C = A @ Bt^T ----------------
// Block tile 128(M) x 256(N), 4 waves: wm=(wave&1)*64, wn=(wave>>1)*128.
__global__ __launch_bounds__(256, 2) void gemm16_kernel(
    const _Float16* __restrict__ A, const _Float16* __restrict__ Bt,
    _Float16* __restrict__ C) {
  __shared__ __align__(16) _Float16 sA[8 * 512];    // 8 A-panels (16 rows x 32 k)
  __shared__ __align__(16) _Float16 sB[16 * 512];   // 16 B-panels
  const int tid = threadIdx.x;
  const int wave = tid >> 6, lane = tid & 63;
  const int bm = blockIdx.y * 128, bn = blockIdx.x * 256;
  const int wm = (wave & 1) * 64, wn = (wave >> 1) * 128;
  const int lr = lane & 15, lc = (lane >> 4) * 8;
  const int fr = lane & 15, quad = lane >> 4;

  f32x4 acc[4][8];
#pragma unroll
  for (int i = 0; i < 4; i++)
#pragma unroll
    for (int j = 0; j < 8; j++) {
      f32x4 z = {0.f, 0.f, 0.f, 0.f};
      acc[i][j] = z;
    }

  for (int k0 = 0; k0 < SEG; k0 += 32) {
    // stage 24 panels (8 A + 16 B), 6 per wave, fragment-major
#pragma unroll
    for (int j = 0; j < 6; j++) {
      int idx = wave * 6 + j;
      bool isA = idx < 8;
      int p = isA ? idx : idx - 8;
      const _Float16* src = isA
          ? (A + (size_t)(bm + p * 16 + lr) * SEG + k0 + lc)
          : (Bt + (size_t)(bn + p * 16 + lr) * SEG + k0 + lc);
      _Float16* dst = isA ? &sA[idx * 512] : &sB[p * 512];
      gload16(src, dst);
    }
    __syncthreads();
    half8 af[4];
#pragma unroll
    for (int i = 0; i < 4; i++)
      af[i] = *(const half8*)&sA[((wm >> 4) + i) * 512 + lane * 8];
#pragma unroll
    for (int j = 0; j < 8; j++) {
      half8 bf = *(const half8*)&sB[((wn >> 4) + j) * 512 + lane * 8];
#pragma unroll
      for (int i = 0; i < 4; i++)
        acc[i][j] = __builtin_amdgcn_mfma_f32_16x16x32_f16(af[i], bf, acc[i][j], 0, 0, 0);
    }
    __syncthreads();
  }
#pragma unroll
  for (int i = 0; i < 4; i++)
#pragma unroll
    for (int j = 0; j < 8; j++) {
      int n = bn + wn + j * 16 + fr;
      if (n >= SEG) continue;
#pragma unroll
      for (int r = 0; r < 4; r++) {
        int m = bm + wm + i * 16 + quad * 4 + r;
        C[(size_t)m * SEG + n] = (_Float16)acc[i][j][r];
      }
    }
}

// ---------------- edge aggregation on fp16 m, fp32 accumulate, fp16 out ----------------
__global__ void agg16_kernel(const _Float16* __restrict__ m, const int* __restrict__ row_off,
                             const int* __restrict__ csr_src, _Float16* __restrict__ agg) {
  int node = blockIdx.x;
  int s = row_off[node], e = row_off[node + 1];
  int tid = threadIdx.x;
  bool act = tid < (SEG / 8);   // 252
  float a[8] = {0, 0, 0, 0, 0, 0, 0, 0};
  __shared__ int s_src[256];
  for (int base = s; base < e; base += 256) {
    int cnt = min(256, e - base);
    __syncthreads();
    if (tid < cnt) s_src[tid] = csr_src[base + tid];
    __syncthreads();
    for (int p = 0; p < cnt; p++) {
      if (act) {
        half8 v = *(const half8*)&m[(size_t)s_src[p] * SEG + tid * 8];
#pragma unroll
        for (int i = 0; i < 8; i++) a[i] += (float)v[i];
      }
    }
  }
  if (act) {
    half8 o;
#pragma unroll
    for (int i = 0; i < 8; i++) o[i] = (_Float16)a[i];
    *(half8*)&agg[(size_t)node * SEG + tid * 8] = o;
  }
}

// ---------------- fused GRU: concat-K GEMM, gate-interleaved N, panel-major LDS ----------------
// Block tile 128(M) x 256(N-packed); wave = 64 rows x 128 cols = 2 colgroups x 4 gates.
__global__ __launch_bounds__(256, 2) void gru16b_kernel(
    const _Float16* __restrict__ Agg, const _Float16* __restrict__ Hc,
    const _Float16* __restrict__ Wp,
    const float* __restrict__ b_ih, const float* __restrict__ b_hh,
    _Float16* __restrict__ Hn) {
  __shared__ __align__(16) _Float16 sA[8 * 512];
  __shared__ __align__(16) _Float16 sB[16 * 512];
  const int tid = threadIdx.x;
  const int wave = tid >> 6, lane = tid & 63;
  const int bm = blockIdx.y * 128, bn = blockIdx.x * 256;
  const int wm = (wave & 1) * 64, wn = (wave >> 1) * 128;
  const int lr = lane & 15, lc = (lane >> 4) * 8;
  const int fr = lane & 15, quad = lane >> 4;

  f32x4 acc[4][8];   // [row-tile][cg*4 + gate]
#pragma unroll
  for (int i = 0; i < 4; i++)
#pragma unroll
    for (int j = 0; j < 8; j++) {
      f32x4 z = {0.f, 0.f, 0.f, 0.f};
      acc[i][j] = z;
    }

  for (int k0 = 0; k0 < KK2; k0 += 32) {
    const bool first = (k0 < 2016);
    const int kk = first ? k0 : (k0 - 2016);
    const _Float16* Ab = first ? Agg : Hc;
#pragma unroll
    for (int j = 0; j < 6; j++) {
      int idx = wave * 6 + j;
      bool isA = idx < 8;
      int p = isA ? idx : idx - 8;
      const _Float16* src = isA
          ? (Ab + (size_t)(bm + p * 16 + lr) * SEG + kk + lc)
          : (Wp + (size_t)(bn + p * 16 + lr) * KK2 + k0 + lc);
      _Float16* dst = isA ? &sA[idx * 512] : &sB[p * 512];
      gload16(src, dst);
    }
    __syncthreads();
    half8 af[4];
#pragma unroll
    for (int i = 0; i < 4; i++)
      af[i] = *(const half8*)&sA[((wm >> 4) + i) * 512 + lane * 8];
    // active gates: first half -> {0,1,2}; second half -> {0,1,3}
#pragma unroll
    for (int cg = 0; cg < 2; cg++) {
#pragma unroll
      for (int gg = 0; gg < 3; gg++) {
        int gate = (gg == 2) ? (first ? 2 : 3) : gg;
        int jt = cg * 4 + gate;
        half8 bf = *(const half8*)&sB[((wn >> 4) + jt) * 512 + lane * 8];
#pragma unroll
        for (int i = 0; i < 4; i++)
          acc[i][jt] = __builtin_amdgcn_mfma_f32_16x16x32_f16(af[i], bf, acc[i][jt], 0, 0, 0);
      }
    }
    __syncthreads();
  }

  const int hbase = (bn + wn) >> 2;   // (bn+wn)/64*16
#pragma unroll
  for (int cg = 0; cg < 2; cg++) {
    int c = hbase + cg * 16 + fr;
    if (c >= H) continue;
    const float b_r = b_ih[c] + b_hh[c];
    const float b_z = b_ih[H + c] + b_hh[H + c];
    const float b_in = b_ih[2 * H + c];
    const float b_hn = b_hh[2 * H + c];
#pragma unroll
    for (int i = 0; i < 4; i++) {
#pragma unroll
      for (int r = 0; r < 4; r++) {
        int m = bm + wm + i * 16 + quad * 4 + r;
        float rg = 1.f / (1.f + expf(-(acc[i][cg * 4 + 0][r] + b_r)));
        float zg = 1.f / (1.f + expf(-(acc[i][cg * 4 + 1][r] + b_z)));
        float nn = tanhf(acc[i][cg * 4 + 2][r] + b_in + rg * (acc[i][cg * 4 + 3][r] + b_hn));
        float hold = (float)Hc[(size_t)m * SEG + c];
        Hn[(size_t)m * SEG + c] = (_Float16)((1.f - zg) * nn + zg * hold);
      }
    }
  }
}

// ---------------- relu + segment max pool (fp16 in, fp32 out) ----------------
__global__ void pool16_kernel(const _Float16* __restrict__ h, const int* __restrict__ starts,
                              float* __restrict__ pooled) {
  int b = blockIdx.x;
  int s = starts[b], e = starts[b + 1];
  for (int idx = threadIdx.x; idx < H; idx += 256) {
    float mx = 0.f;  // relu floor
    for (int n = s; n < e; n++) mx = fmaxf(mx, (float)h[(size_t)n * SEG + idx]);
    pooled[b * H + idx] = mx;
  }
}

// ---------------- conv / linear tail (fp32) ----------------
__global__ void conv1_kernel(const float* __restrict__ in, const float* __restrict__ w,
                             const float* __restrict__ bias, float* __restrict__ outp) {
  __shared__ float sin_[H];
  int b = blockIdx.x;
  for (int j = threadIdx.x; j < H; j += 256) sin_[j] = in[(size_t)b * H + j];
  __syncthreads();
  for (int idx = threadIdx.x; idx < C1_OC * C1_L; idx += 256) {
    int oc = idx / C1_L, t = idx % C1_L;
    float w0 = w[oc * 3], w1 = w[oc * 3 + 1], w2 = w[oc * 3 + 2];
    float bb = bias[oc];
    float best = 0.f;
    int base = t * 3;
#pragma unroll
    for (int p = 0; p < 3; p++) {
      float v = fmaf(sin_[base + p], w0, fmaf(sin_[base + p + 1], w1,
                fmaf(sin_[base + p + 2], w2, bb)));
      best = fmaxf(best, v);
    }
    outp[((size_t)b * C1_OC + oc) * C1_L + t] = best;
  }
}

__global__ void conv2_kernel(const float* __restrict__ in, const float* __restrict__ w,
                             const float* __restrict__ bias, float* __restrict__ outp) {
  int idx = blockIdx.x * 256 + threadIdx.x;
  if (idx >= NB * C2_OC * C2_L) return;
  int t = idx % C2_L;
  int rem = idx / C2_L;
  int oc = rem % C2_OC;
  int b = rem / C2_OC;
  const float* ip = in + (size_t)b * C1_OC * C1_L;
  const float* wp = w + oc * C1_OC * 3;
  float bb = bias[oc];
  float s0 = bb, s1 = bb, s2 = bb;
  int tc = t * 3;
  for (int ic = 0; ic < C1_OC; ic++) {
    const float* r = ip + ic * C1_L + tc;
    float v0 = r[0], v1 = r[1], v2 = r[2], v3 = r[3], v4 = r[4];
    float w0 = wp[ic * 3], w1 = wp[ic * 3 + 1], w2 = wp[ic * 3 + 2];
    s0 = fmaf(v0, w0, fmaf(v1, w1, fmaf(v2, w2, s0)));
    s1 = fmaf(v1, w0, fmaf(v2, w1, fmaf(v3, w2, s1)));
    s2 = fmaf(v2, w0, fmaf(v3, w1, fmaf(v4, w2, s2)));
  }
  outp[idx] = fmaxf(fmaxf(s0, fmaxf(s1, s2)), 0.f);
}

__global__ void conv3_kernel(const float* __restrict__ in, const float* __restrict__ w,
                             const float* __restrict__ bias, float* __restrict__ outp) {
  int idx = blockIdx.x * 256 + threadIdx.x;
  if (idx >= NB * C3_OC * C3_L) return;
  int t = idx % C3_L;
  int rem = idx / C3_L;
  int oc = rem % C3_OC;
  int b = rem / C3_OC;
  const float* ip = in + (size_t)b * C2_OC * C2_L;
  const float* wp = w + oc * C2_OC * 3;
  float bb = bias[oc];
  float s0 = bb, s1 = bb, s2 = bb;
  int tc = t * 3;
  for (int ic = 0; ic < C2_OC; ic++) {
    const float* r = ip + ic * C2_L + tc;
    float v0 = r[0], v1 = r[1], v2 = r[2], v3 = r[3], v4 = r[4];
    float w0 = wp[ic * 3], w1 = wp[ic * 3 + 1], w2 = wp[ic * 3 + 2];
    s0 = fmaf(v0, w0, fmaf(v1, w1, fmaf(v2, w2, s0)));
    s1 = fmaf(v1, w0, fmaf(v2, w1, fmaf(v3, w2, s1)));
    s2 = fmaf(v2, w0, fmaf(v3, w1, fmaf(v4, w2, s2)));
  }
  outp[idx] = fmaxf(fmaxf(s0, fmaxf(s1, s2)), 0.f);
}

__global__ void lin1_kernel(const float* __restrict__ x, const float* __restrict__ w,
                            const float* __restrict__ bias, float* __restrict__ outp) {
  int gid = blockIdx.x * 4 + (threadIdx.x >> 6);
  int lane = threadIdx.x & 63;
  int b = gid / LIN1_OUT;
  int o = gid % LIN1_OUT;
  const float* xp = x + (size_t)b * LIN1_IN;
  const float* wp = w + (size_t)o * LIN1_IN;
  float s = 0.f;
  for (int k = lane; k < LIN1_IN; k += 64) s = fmaf(xp[k], wp[k], s);
#pragma unroll
  for (int off = 32; off > 0; off >>= 1) s += __shfl_down(s, off, 64);
  if (lane == 0) outp[b * LIN1_OUT + o] = fmaxf(s + bias[o], 0.f);
}

__global__ void lin2_kernel(const float* __restrict__ x, const float* __restrict__ w,
                            const float* __restrict__ bias, float* __restrict__ outp) {
  int tid = threadIdx.x;
  int b = tid >> 2, o = tid & 3;
  const float* xp = x + b * LIN1_OUT;
  const float* wp = w + o * LIN1_OUT;
  float s = bias[o];
  for (int k = 0; k < LIN1_OUT; k++) s = fmaf(xp[k], wp[k], s);
  outp[b * 4 + o] = fmaxf(s, 0.f);
}

// ================= launch =================
extern "C" void kernel_launch(void* const* d_in, const int* in_sizes, int n_in,
                              void* d_out, int out_size, void* d_ws, size_t ws_size,
                              hipStream_t stream) {
  const int* tokens = (const int*)d_in[0];
  const int* edge_index = (const int*)d_in[1];
  const int* batch = (const int*)d_in[2];
  const float* embed = (const float*)d_in[3];
  const float* W_ggc = (const float*)d_in[4];
  const float* W_ih = (const float*)d_in[5];
  const float* W_hh = (const float*)d_in[6];
  const float* b_ih = (const float*)d_in[7];
  const float* b_hh = (const float*)d_in[8];
  const float* c1w = (const float*)d_in[9];
  const float* c1b = (const float*)d_in[10];
  const float* c2w = (const float*)d_in[11];
  const float* c2b = (const float*)d_in[12];
  const float* c3w = (const float*)d_in[13];
  const float* c3b = (const float*)d_in[14];
  const float* l1w = (const float*)d_in[15];
  const float* l1b = (const float*)d_in[16];
  const float* l2w = (const float*)d_in[17];
  const float* l2b = (const float*)d_in[18];
  float* out = (float*)d_out;

  const int* e_src = edge_index;
  const int* e_dst = edge_index + N_EDGES;

  char* ws = (char*)d_ws;
  size_t off = 0;
  auto alloc = [&](size_t bytes) -> void* {
    void* p = ws + off;
    off = (off + bytes + 255) & ~(size_t)255;
    return p;
  };

  const size_t ACT = sizeof(_Float16) * (size_t)MP * SEG;   // 40.77 MB
  _Float16* bufX = (_Float16*)alloc(ACT);                   // h (current)
  _Float16* bufY = (_Float16*)alloc(ACT);                   // m / h_next (rotates with X)
  _Float16* bufZ = (_Float16*)alloc(ACT);                   // agg (fixed)
  _Float16* Wg_b = (_Float16*)alloc(sizeof(_Float16) * (size_t)LAYERS * NW * SEG);  // 33 MB
  _Float16* Wp   = (_Float16*)alloc(sizeof(_Float16) * (size_t)NPACK * KK2);        // 66 MB
  int* counts = (int*)alloc(sizeof(int) * (N_NODES + 1));
  int* row_off = (int*)alloc(sizeof(int) * (N_NODES + 1));
  int* cursor = (int*)alloc(sizeof(int) * N_NODES);
  int* csr_src = (int*)alloc(sizeof(int) * N_EDGES);
  int* starts = (int*)alloc(sizeof(int) * (NB + 1));

  // tail buffers alias bufZ (agg dead after last gru): 17.6 MB < 40.77 MB
  char* tb = (char*)bufZ;
  size_t toff = 0;
  auto talloc = [&](size_t bytes) -> void* {
    void* p = tb + toff;
    toff = (toff + bytes + 255) & ~(size_t)255;
    return p;
  };
  float* pooled = (float*)talloc(sizeof(float) * NB * H);
  float* c1 = (float*)talloc(sizeof(float) * (size_t)NB * C1_OC * C1_L);
  float* c2 = (float*)talloc(sizeof(float) * (size_t)NB * C2_OC * C2_L);
  float* c3 = (float*)talloc(sizeof(float) * (size_t)NB * C3_OC * C3_L);
  float* l1out = (float*)talloc(sizeof(float) * NB * LIN1_OUT);

  hipMemsetAsync(counts, 0, sizeof(int) * (N_NODES + 1), stream);
  hipMemsetAsync(cursor, 0, sizeof(int) * N_NODES, stream);

  // weight prep
  {
    dim3 gg(SEG / 32, NW / 32, LAYERS);
    prep_wg16_kernel<<<gg, 256, 0, stream>>>(W_ggc, Wg_b);
    dim3 gp((KK2 + 255) / 256, NPACK);
    prep_wpack_kernel<<<gp, 256, 0, stream>>>(W_ih, W_hh, Wp);
  }

  embed16_kernel<<<N_NODES, 256, 0, stream>>>(tokens, embed, bufX);
  hist_kernel<<<(N_EDGES + 255) / 256, 256, 0, stream>>>(e_dst, counts, N_EDGES);
  scan_kernel<<<1, 1024, 0, stream>>>(counts, row_off, N_NODES);
  scatter_kernel<<<(N_EDGES + 255) / 256, 256, 0, stream>>>(e_src, e_dst, row_off, cursor,
                                                            csr_src, N_EDGES);
  starts_kernel<<<(N_NODES + 255) / 256, 256, 0, stream>>>(batch, starts, N_NODES);

  dim3 grid_m(NW / 256, MP / 128);        // 8 x 79
  dim3 grid_gru(NPACK / 256, MP / 128);   // 32 x 79
  _Float16* X = bufX;
  _Float16* Y = bufY;
  for (int l = 0; l < LAYERS; l++) {
    gemm16_kernel<<<grid_m, 256, 0, stream>>>(X, Wg_b + (size_t)l * NW * SEG, Y);
    agg16_kernel<<<N_NODES, 256, 0, stream>>>(Y, row_off, csr_src, bufZ);
    gru16b_kernel<<<grid_gru, 256, 0, stream>>>(bufZ, X, Wp, b_ih, b_hh, Y);
    _Float16* t = X; X = Y; Y = t;
  }
  // X holds final h

  pool16_kernel<<<NB, 256, 0, stream>>>(X, starts, pooled);
  conv1_kernel<<<NB, 256, 0, stream>>>(pooled, c1w, c1b, c1);
  conv2_kernel<<<(NB * C2_OC * C2_L + 255) / 256, 256, 0, stream>>>(c1, c2w, c2b, c2);
  conv3_kernel<<<(NB * C3_OC * C3_L + 255) / 256, 256, 0, stream>>>(c2, c3w, c3b, c3);
  lin1_kernel<<<NB * LIN1_OUT / 4, 256, 0, stream>>>(c3, l1w, l1b, l1out);
  lin2_kernel<<<1, 256, 0, stream>>>(l1out, l2w, l2b, out);
}